// Round 3
// baseline (4094.979 us; speedup 1.0000x reference)
//
#include <hip/hip_runtime.h>

// Problem constants (from reference setup_inputs)
static constexpr int B = 4, C = 3, H = 1080, W = 1920;
static constexpr int HW = H * W;          // 2,073,600
static constexpr int NPIX = B * HW;       // 8,294,400
static constexpr int BLOCK = 256;

// Target-domain tiling for the binned splat. Tile 64x32 -> LDS use is
// 8 KB (dmax) + 32 KB (acc) = 40 KB -> 4 WG/CU (50% occupancy).
static constexpr int TW = 64, TH = 32;
static constexpr int TPX = TW * TH;              // 2048
static constexpr int TXN = W / TW;               // 30 (exact)
static constexpr int TYN = (H + TH - 1) / TH;    // 34 (last tile 24 rows)
static constexpr int NT = TXN * TYN;             // 1020 tiles per batch
static constexpr int CAP = 4096;                 // entries/bin; mean ~2145, sigma ~46
static constexpr int OFL_CAP = 65536;            // overflow list capacity

// Depth key must match numpy bit-exactly: no FMA contraction, round-half-even.
// Winner selection is an exact integer compare -> identical everywhere.
__device__ __forceinline__ int depth_key(float fx, float fy) {
    float m2 = __fadd_rn(__fmul_rn(fx, fx), __fmul_rn(fy, fy));
    return (int)rintf(__fmul_rn(sqrtf(m2), 1000.0f));
}

// ---------------------------------------------------------------------------
// Pass 1: bin every source pixel into the tile(s) its 2x2 corner footprint
// touches (1..4 tiles, ~1.05 avg). Handles ANY flow magnitude (no window
// containment needed). Bin overflow (never expected): depth contribution goes
// straight to global dbuf, accumulation deferred to the overflow list.
__global__ __launch_bounds__(BLOCK) void k_bin(const float2* __restrict__ flow,
                                               int* __restrict__ cnt,
                                               int* __restrict__ bin,
                                               int* __restrict__ ofl_cnt,
                                               int* __restrict__ ofl_i,
                                               int* __restrict__ ofl_t,
                                               int* __restrict__ dbuf) {
    int i = blockIdx.x * BLOCK + threadIdx.x;
    if (i >= NPIX) return;
    int b = i / HW;
    int pix = i - b * HW;
    int h = pix / W;
    int w = pix - h * W;
    float2 f = flow[i];
    float x = (float)w + f.x;
    float y = (float)h + f.y;
    int x0 = (int)floorf(x);
    int y0 = (int)floorf(y);

    int tl[4]; int ntl = 0;
    #pragma unroll
    for (int dy = 0; dy < 2; ++dy) {
        int cy = y0 + dy;
        if ((unsigned)cy >= (unsigned)H) continue;
        #pragma unroll
        for (int dx = 0; dx < 2; ++dx) {
            int cx = x0 + dx;
            if ((unsigned)cx >= (unsigned)W) continue;
            int t = (cy >> 5) * TXN + (cx >> 6);
            bool dup = false;
            for (int k = 0; k < ntl; ++k) dup |= (tl[k] == t);
            if (dup) continue;
            tl[ntl++] = t;
            int bidx = b * NT + t;
            int slot = atomicAdd(&cnt[bidx], 1);
            if (slot < CAP) {
                bin[(size_t)bidx * CAP + slot] = pix;
            } else {
                int pos = atomicAdd(ofl_cnt, 1);
                if (pos < OFL_CAP) { ofl_i[pos] = i; ofl_t[pos] = t; }
                // Depth must be merged before k_tile: contribute all in-bounds
                // corners directly (repeat-safe for multi-tile overflow).
                int d = depth_key(f.x, f.y);
                #pragma unroll
                for (int yy = 0; yy < 2; ++yy) {
                    int cy2 = y0 + yy;
                    if ((unsigned)cy2 >= (unsigned)H) continue;
                    #pragma unroll
                    for (int xx = 0; xx < 2; ++xx) {
                        int cx2 = x0 + xx;
                        if ((unsigned)cx2 >= (unsigned)W) continue;
                        atomicMax(&dbuf[b * HW + cy2 * W + cx2], d);
                    }
                }
            }
        }
    }
}

// ---------------------------------------------------------------------------
// Pass 2: fused depth+accumulate per tile, driven by the bin.
// dmax init from dbuf (carries overflow contributions), scan bin for LDS
// depth max, publish merged dbuf, re-scan bin (flow L1-hot) for depth-tested
// LDS accumulation. If no overflow anywhere (the always case) the normalized
// output is written directly and the norm pass self-disables.
__global__ __launch_bounds__(BLOCK) void k_tile(const float* __restrict__ im0,
                                                const float2* __restrict__ flow,
                                                const int* __restrict__ cnt,
                                                const int* __restrict__ bin,
                                                const int* __restrict__ ofl_cnt,
                                                int* __restrict__ dbuf,
                                                float* __restrict__ wght,
                                                float* __restrict__ out) {
    __shared__ int   dmax[TPX];       // 8 KB
    __shared__ float acc[4][TPX];     // 32 KB  (w, c0, c1, c2)
    const int tid = threadIdx.x;
    const int bx = blockIdx.x, by = blockIdx.y, b = blockIdx.z;
    const int tx0 = bx * TW, ty0 = by * TH;
    const int t = by * TXN + bx;
    int* db = dbuf + (size_t)b * HW;

    for (int i = tid; i < TPX; i += BLOCK) {
        int gy = ty0 + (i >> 6), gx = tx0 + (i & 63);
        dmax[i] = (gy < H) ? db[gy * W + gx] : 0;
        acc[0][i] = 0.0f; acc[1][i] = 0.0f; acc[2][i] = 0.0f; acc[3][i] = 0.0f;
    }
    __syncthreads();

    const int n = min(cnt[b * NT + t], CAP);
    const int* mybin = bin + (size_t)(b * NT + t) * CAP;
    const float2* fb = flow + (size_t)b * HW;

    // scan 1: depth max into LDS
    for (int e = tid; e < n; e += BLOCK) {
        int pix = mybin[e];
        int h = pix / W, w = pix - h * W;
        float2 f = fb[pix];
        float x = (float)w + f.x;
        float y = (float)h + f.y;
        int x0 = (int)floorf(x);
        int y0 = (int)floorf(y);
        int d = depth_key(f.x, f.y);
        #pragma unroll
        for (int dy = 0; dy < 2; ++dy) {
            int cy = y0 + dy;
            if ((cy >> 5) != by || cy >= H) continue;
            #pragma unroll
            for (int dx = 0; dx < 2; ++dx) {
                int cx = x0 + dx;
                if ((cx >> 6) != bx) continue;
                atomicMax(&dmax[((cy - ty0) << 6) + (cx - tx0)], d);
            }
        }
    }
    __syncthreads();

    // publish merged depth (needed by overflow-accum kernel; tiles partition
    // the image so plain coalesced stores suffice)
    for (int i = tid; i < TPX; i += BLOCK) {
        int gy = ty0 + (i >> 6), gx = tx0 + (i & 63);
        if (gy < H) db[gy * W + gx] = dmax[i];
    }

    // scan 2: depth-tested accumulation (dmax read-only from here; no race
    // with the store loop above)
    const float* ib = im0 + (size_t)b * C * HW;
    for (int e = tid; e < n; e += BLOCK) {
        int pix = mybin[e];
        int h = pix / W, w = pix - h * W;
        float2 f = fb[pix];
        float x = (float)w + f.x;
        float y = (float)h + f.y;
        float x0f = floorf(x), y0f = floorf(y);
        int x0 = (int)x0f, y0 = (int)y0f;
        float ax = __fsub_rn(x, x0f);
        float ay = __fsub_rn(y, y0f);
        int d = depth_key(f.x, f.y);
        float wxv[2] = { __fsub_rn(1.0f, ax), ax };
        float wyv[2] = { __fsub_rn(1.0f, ay), ay };
        int   locs[4]; float lw[4]; int nw = 0;
        #pragma unroll
        for (int dy = 0; dy < 2; ++dy) {
            int cy = y0 + dy;
            if ((cy >> 5) != by || cy >= H) continue;
            #pragma unroll
            for (int dx = 0; dx < 2; ++dx) {
                int cx = x0 + dx;
                if ((cx >> 6) != bx) continue;
                int loc = ((cy - ty0) << 6) + (cx - tx0);
                if (dmax[loc] != d) continue;
                locs[nw] = loc;
                lw[nw] = __fmul_rn(wxv[dx], wyv[dy]);
                ++nw;
            }
        }
        if (nw) {
            float c0 = ib[pix];
            float c1 = ib[pix + HW];
            float c2 = ib[pix + 2 * HW];
            for (int k = 0; k < nw; ++k) {
                int p = locs[k]; float wg = lw[k];
                atomicAdd(&acc[0][p], wg);
                atomicAdd(&acc[1][p], __fmul_rn(c0, wg));
                atomicAdd(&acc[2][p], __fmul_rn(c1, wg));
                atomicAdd(&acc[3][p], __fmul_rn(c2, wg));
            }
        }
    }
    __syncthreads();

    const bool raw = (*ofl_cnt) > 0;   // uniform across grid, input-determined
    float* ob = out + (size_t)b * C * HW;
    float* wb = wght + (size_t)b * HW;
    for (int i = tid; i < TPX; i += BLOCK) {
        int gy = ty0 + (i >> 6), gx = tx0 + (i & 63);
        if (gy >= H) continue;
        int g = gy * W + gx;
        float a0 = acc[0][i], a1 = acc[1][i], a2 = acc[2][i], a3 = acc[3][i];
        if (raw) {  // overflow exists: store raw sums, norm pass finishes
            wb[g] = a0;
            ob[g] = a1; ob[g + HW] = a2; ob[g + 2 * HW] = a3;
        } else {    // common case: fused normalize (same ops as k_norm)
            float wv = fmaxf(a0, 1e-5f);
            ob[g]          = __fdiv_rn(a1, wv);
            ob[g + HW]     = __fdiv_rn(a2, wv);
            ob[g + 2 * HW] = __fdiv_rn(a3, wv);
        }
    }
}

// ---------------------------------------------------------------------------
// Overflow accumulation (normally zero work): global atomics, corners
// restricted to the overflowed tile (other tiles own their own copies).
__global__ __launch_bounds__(BLOCK) void k_accum_ofl(const float* __restrict__ im0,
                                                     const float2* __restrict__ flow,
                                                     const int* __restrict__ ofl_cnt,
                                                     const int* __restrict__ ofl_i,
                                                     const int* __restrict__ ofl_t,
                                                     const int* __restrict__ dbuf,
                                                     float* __restrict__ wght,
                                                     float* __restrict__ out) {
    int k = blockIdx.x * BLOCK + threadIdx.x;
    int n = min(*ofl_cnt, OFL_CAP);
    if (k >= n) return;
    int i = ofl_i[k], t = ofl_t[k];
    int b = i / HW;
    int pix = i - b * HW;
    int h = pix / W, w = pix - h * W;
    int bx = t % TXN, by = t / TXN;
    float2 f = flow[i];
    float x = (float)w + f.x;
    float y = (float)h + f.y;
    float x0f = floorf(x), y0f = floorf(y);
    int x0 = (int)x0f, y0 = (int)y0f;
    float ax = __fsub_rn(x, x0f);
    float ay = __fsub_rn(y, y0f);
    int d = depth_key(f.x, f.y);
    const float* src = im0 + (size_t)b * C * HW + pix;
    float c0 = src[0], c1 = src[HW], c2 = src[2 * HW];
    float wxv[2] = { __fsub_rn(1.0f, ax), ax };
    float wyv[2] = { __fsub_rn(1.0f, ay), ay };
    #pragma unroll
    for (int dy = 0; dy < 2; ++dy) {
        int cy = y0 + dy;
        if ((cy >> 5) != by || cy >= H) continue;
        #pragma unroll
        for (int dx = 0; dx < 2; ++dx) {
            int cx = x0 + dx;
            if ((cx >> 6) != bx) continue;
            int idx = b * HW + cy * W + cx;
            if (dbuf[idx] != d) continue;
            float wg = __fmul_rn(wxv[dx], wyv[dy]);
            atomicAdd(&wght[idx], wg);
            float* o = out + (size_t)b * C * HW + cy * W + cx;
            atomicAdd(&o[0],      __fmul_rn(c0, wg));
            atomicAdd(&o[HW],     __fmul_rn(c1, wg));
            atomicAdd(&o[2 * HW], __fmul_rn(c2, wg));
        }
    }
}

// Norm pass: only active when overflow occurred (k_tile stored raw sums).
__global__ __launch_bounds__(BLOCK) void k_norm(float* __restrict__ out,
                                                const float* __restrict__ wght,
                                                const int* __restrict__ ofl_cnt) {
    if (*ofl_cnt == 0) return;
    int i = blockIdx.x * BLOCK + threadIdx.x;
    if (i >= NPIX) return;
    int b = i / HW;
    int pix = i - b * HW;
    float wv = fmaxf(wght[i], 1e-5f);
    float* o = out + (size_t)b * C * HW + pix;
    o[0]      = __fdiv_rn(o[0], wv);
    o[HW]     = __fdiv_rn(o[HW], wv);
    o[2 * HW] = __fdiv_rn(o[2 * HW], wv);
}

extern "C" void kernel_launch(void* const* d_in, const int* in_sizes, int n_in,
                              void* d_out, int out_size, void* d_ws, size_t ws_size,
                              hipStream_t stream) {
    const float*  im0  = (const float*)d_in[0];   // [B,C,H,W]
    const float2* flow = (const float2*)d_in[1];  // [B,H,W,2] as float2
    float* out = (float*)d_out;                   // [B,C,H,W]

    // Workspace layout (bytes):
    char* ws = (char*)d_ws;
    int*   dbuf    = (int*)ws;                                   // NPIX
    float* wght    = (float*)(ws + (size_t)NPIX * 4);            // NPIX
    int*   cnt     = (int*)(ws + (size_t)NPIX * 8);              // B*NT
    int*   ofl_cnt = cnt + B * NT;                               // 1 (adjacent to cnt)
    int*   ofl_i   = ofl_cnt + 1;                                // OFL_CAP
    int*   ofl_t   = ofl_i + OFL_CAP;                            // OFL_CAP
    int*   bin     = ofl_t + OFL_CAP;                            // B*NT*CAP (~67 MB)

    hipMemsetAsync(dbuf, 0, (size_t)NPIX * 4, stream);
    hipMemsetAsync(cnt, 0, (size_t)(B * NT + 1) * 4, stream);

    int lgrid = (NPIX + BLOCK - 1) / BLOCK;
    dim3 tgrid(TXN, TYN, B);

    k_bin      <<<lgrid, BLOCK, 0, stream>>>(flow, cnt, bin, ofl_cnt, ofl_i, ofl_t, dbuf);
    k_tile     <<<tgrid, BLOCK, 0, stream>>>(im0, flow, cnt, bin, ofl_cnt, dbuf, wght, out);
    k_accum_ofl<<<OFL_CAP / BLOCK, BLOCK, 0, stream>>>(im0, flow, ofl_cnt, ofl_i, ofl_t, dbuf, wght, out);
    k_norm     <<<lgrid, BLOCK, 0, stream>>>(out, wght, ofl_cnt);
}

// Round 4
// 524.819 us; speedup vs baseline: 7.8027x; 7.8027x over previous
//
#include <hip/hip_runtime.h>

// Problem constants (from reference setup_inputs)
static constexpr int B = 4, C = 3, H = 1080, W = 1920;
static constexpr int HW = H * W;          // 2,073,600
static constexpr int NPIX = B * HW;       // 8,294,400
static constexpr int BLOCK = 256;

// Target-domain tiling for the binned splat. Tile 64x32 -> k_tile LDS use is
// 8 KB (dmax) + 32 KB (acc) = 40 KB -> 4 WG/CU.
static constexpr int TW = 64, TH = 32;
static constexpr int TPX = TW * TH;              // 2048
static constexpr int TXN = W / TW;               // 30 (exact)
static constexpr int TYN = (H + TH - 1) / TH;    // 34 (last tile 24 rows)
static constexpr int NT = TXN * TYN;             // 1020 tiles per batch
static constexpr int CAP = 4096;                 // entries/bin; mean ~2145, sigma ~46
static constexpr int OFL_CAP = 65536;            // overflow list capacity
static constexpr int BPB = HW / BLOCK;           // 8100 blocks per batch (exact)

// Depth key must match numpy bit-exactly: no FMA contraction, round-half-even.
// Winner selection is an exact integer compare -> identical everywhere.
__device__ __forceinline__ int depth_key(float fx, float fy) {
    float m2 = __fadd_rn(__fmul_rn(fx, fx), __fmul_rn(fy, fy));
    return (int)rintf(__fmul_rn(sqrtf(m2), 1000.0f));
}

// ---------------------------------------------------------------------------
// Pass 1: bin every source pixel into the tile(s) its 2x2 corner footprint
// touches (1..4 tiles, ~1.05 avg), via a per-block LDS histogram so the
// global counter sees ONE atomic per unique tile per block (~0.8M total,
// vs 8.7M per-thread returning atomics that serialized round 3 at 4 ms).
__global__ __launch_bounds__(BLOCK) void k_bin(const float2* __restrict__ flow,
                                               int* __restrict__ cnt,
                                               int* __restrict__ bin,
                                               int* __restrict__ ofl_cnt,
                                               int* __restrict__ ofl_i,
                                               int* __restrict__ ofl_t,
                                               int* __restrict__ dbuf) {
    __shared__ int hcnt[NT];    // 4080 B: per-block per-tile count
    __shared__ int hbase[NT];   // 4080 B: global base slot for this block
    const int tid = threadIdx.x;
    for (int j = tid; j < NT; j += BLOCK) hcnt[j] = 0;
    __syncthreads();

    const int b = blockIdx.x / BPB;               // all threads in block share b
    const int i = blockIdx.x * BLOCK + tid;
    const int pix = i - b * HW;
    const int h = pix / W;
    const int w = pix - h * W;
    const float2 f = flow[i];
    const float x = (float)w + f.x;
    const float y = (float)h + f.y;
    const int x0 = (int)floorf(x);
    const int y0 = (int)floorf(y);

    // Phase 1: dedup'd tile list + rank within block (LDS atomics).
    int tl[4], rk[4]; int ntl = 0;
    #pragma unroll
    for (int dy = 0; dy < 2; ++dy) {
        int cy = y0 + dy;
        if ((unsigned)cy >= (unsigned)H) continue;
        #pragma unroll
        for (int dx = 0; dx < 2; ++dx) {
            int cx = x0 + dx;
            if ((unsigned)cx >= (unsigned)W) continue;
            int t = (cy >> 5) * TXN + (cx >> 6);
            bool dup = false;
            for (int k = 0; k < ntl; ++k) dup |= (tl[k] == t);
            if (dup) continue;
            tl[ntl] = t;
            rk[ntl] = atomicAdd(&hcnt[t], 1);
            ++ntl;
        }
    }
    __syncthreads();

    // Phase 2: one global atomic per touched tile, grab base slots.
    for (int j = tid; j < NT; j += BLOCK) {
        int c = hcnt[j];
        if (c > 0) hbase[j] = atomicAdd(&cnt[b * NT + j], c);
    }
    __syncthreads();

    // Phase 3: write entries at base+rank (consecutive slots per tile per
    // block -> clustered stores). Overflow (never expected): depth merged
    // directly into global dbuf, accumulation deferred to the overflow list.
    bool did_depth_fb = false;
    for (int k = 0; k < ntl; ++k) {
        int t = tl[k];
        int slot = hbase[t] + rk[k];
        if (slot < CAP) {
            bin[(size_t)(b * NT + t) * CAP + slot] = pix;
        } else {
            int pos = atomicAdd(ofl_cnt, 1);
            if (pos < OFL_CAP) { ofl_i[pos] = i; ofl_t[pos] = t; }
            if (!did_depth_fb) {
                did_depth_fb = true;   // corners repeat across tiles; merge once
                int d = depth_key(f.x, f.y);
                #pragma unroll
                for (int yy = 0; yy < 2; ++yy) {
                    int cy2 = y0 + yy;
                    if ((unsigned)cy2 >= (unsigned)H) continue;
                    #pragma unroll
                    for (int xx = 0; xx < 2; ++xx) {
                        int cx2 = x0 + xx;
                        if ((unsigned)cx2 >= (unsigned)W) continue;
                        atomicMax(&dbuf[b * HW + cy2 * W + cx2], d);
                    }
                }
            }
        }
    }
}

// ---------------------------------------------------------------------------
// Pass 2: fused depth+accumulate per tile, driven by the bin.
// dmax init from dbuf (carries overflow contributions), scan bin for LDS
// depth max, publish merged dbuf, re-scan bin (flow L1-hot) for depth-tested
// LDS accumulation. If no overflow anywhere (the always case) the normalized
// output is written directly and the norm pass self-disables.
__global__ __launch_bounds__(BLOCK) void k_tile(const float* __restrict__ im0,
                                                const float2* __restrict__ flow,
                                                const int* __restrict__ cnt,
                                                const int* __restrict__ bin,
                                                const int* __restrict__ ofl_cnt,
                                                int* __restrict__ dbuf,
                                                float* __restrict__ wght,
                                                float* __restrict__ out) {
    __shared__ int   dmax[TPX];       // 8 KB
    __shared__ float acc[4][TPX];     // 32 KB  (w, c0, c1, c2)
    const int tid = threadIdx.x;
    const int bx = blockIdx.x, by = blockIdx.y, b = blockIdx.z;
    const int tx0 = bx * TW, ty0 = by * TH;
    const int t = by * TXN + bx;
    int* db = dbuf + (size_t)b * HW;

    for (int i = tid; i < TPX; i += BLOCK) {
        int gy = ty0 + (i >> 6), gx = tx0 + (i & 63);
        dmax[i] = (gy < H) ? db[gy * W + gx] : 0;
        acc[0][i] = 0.0f; acc[1][i] = 0.0f; acc[2][i] = 0.0f; acc[3][i] = 0.0f;
    }
    __syncthreads();

    const int n = min(cnt[b * NT + t], CAP);
    const int* mybin = bin + (size_t)(b * NT + t) * CAP;
    const float2* fb = flow + (size_t)b * HW;

    // scan 1: depth max into LDS
    for (int e = tid; e < n; e += BLOCK) {
        int pix = mybin[e];
        int h = pix / W, w = pix - h * W;
        float2 f = fb[pix];
        float x = (float)w + f.x;
        float y = (float)h + f.y;
        int x0 = (int)floorf(x);
        int y0 = (int)floorf(y);
        int d = depth_key(f.x, f.y);
        #pragma unroll
        for (int dy = 0; dy < 2; ++dy) {
            int cy = y0 + dy;
            if ((cy >> 5) != by || cy >= H) continue;
            #pragma unroll
            for (int dx = 0; dx < 2; ++dx) {
                int cx = x0 + dx;
                if ((cx >> 6) != bx) continue;
                atomicMax(&dmax[((cy - ty0) << 6) + (cx - tx0)], d);
            }
        }
    }
    __syncthreads();

    // publish merged depth (needed by overflow-accum kernel; tiles partition
    // the image so plain coalesced stores suffice)
    for (int i = tid; i < TPX; i += BLOCK) {
        int gy = ty0 + (i >> 6), gx = tx0 + (i & 63);
        if (gy < H) db[gy * W + gx] = dmax[i];
    }

    // scan 2: depth-tested accumulation (dmax read-only from here; no race
    // with the store loop above)
    const float* ib = im0 + (size_t)b * C * HW;
    for (int e = tid; e < n; e += BLOCK) {
        int pix = mybin[e];
        int h = pix / W, w = pix - h * W;
        float2 f = fb[pix];
        float x = (float)w + f.x;
        float y = (float)h + f.y;
        float x0f = floorf(x), y0f = floorf(y);
        int x0 = (int)x0f, y0 = (int)y0f;
        float ax = __fsub_rn(x, x0f);
        float ay = __fsub_rn(y, y0f);
        int d = depth_key(f.x, f.y);
        float wxv[2] = { __fsub_rn(1.0f, ax), ax };
        float wyv[2] = { __fsub_rn(1.0f, ay), ay };
        int   locs[4]; float lw[4]; int nw = 0;
        #pragma unroll
        for (int dy = 0; dy < 2; ++dy) {
            int cy = y0 + dy;
            if ((cy >> 5) != by || cy >= H) continue;
            #pragma unroll
            for (int dx = 0; dx < 2; ++dx) {
                int cx = x0 + dx;
                if ((cx >> 6) != bx) continue;
                int loc = ((cy - ty0) << 6) + (cx - tx0);
                if (dmax[loc] != d) continue;
                locs[nw] = loc;
                lw[nw] = __fmul_rn(wxv[dx], wyv[dy]);
                ++nw;
            }
        }
        if (nw) {
            float c0 = ib[pix];
            float c1 = ib[pix + HW];
            float c2 = ib[pix + 2 * HW];
            for (int k = 0; k < nw; ++k) {
                int p = locs[k]; float wg = lw[k];
                atomicAdd(&acc[0][p], wg);
                atomicAdd(&acc[1][p], __fmul_rn(c0, wg));
                atomicAdd(&acc[2][p], __fmul_rn(c1, wg));
                atomicAdd(&acc[3][p], __fmul_rn(c2, wg));
            }
        }
    }
    __syncthreads();

    const bool raw = (*ofl_cnt) > 0;   // uniform across grid, input-determined
    float* ob = out + (size_t)b * C * HW;
    float* wb = wght + (size_t)b * HW;
    for (int i = tid; i < TPX; i += BLOCK) {
        int gy = ty0 + (i >> 6), gx = tx0 + (i & 63);
        if (gy >= H) continue;
        int g = gy * W + gx;
        float a0 = acc[0][i], a1 = acc[1][i], a2 = acc[2][i], a3 = acc[3][i];
        if (raw) {  // overflow exists: store raw sums, norm pass finishes
            wb[g] = a0;
            ob[g] = a1; ob[g + HW] = a2; ob[g + 2 * HW] = a3;
        } else {    // common case: fused normalize (same ops as k_norm)
            float wv = fmaxf(a0, 1e-5f);
            ob[g]          = __fdiv_rn(a1, wv);
            ob[g + HW]     = __fdiv_rn(a2, wv);
            ob[g + 2 * HW] = __fdiv_rn(a3, wv);
        }
    }
}

// ---------------------------------------------------------------------------
// Overflow accumulation (normally zero work): global atomics, corners
// restricted to the overflowed tile (other tiles own their own copies).
__global__ __launch_bounds__(BLOCK) void k_accum_ofl(const float* __restrict__ im0,
                                                     const float2* __restrict__ flow,
                                                     const int* __restrict__ ofl_cnt,
                                                     const int* __restrict__ ofl_i,
                                                     const int* __restrict__ ofl_t,
                                                     const int* __restrict__ dbuf,
                                                     float* __restrict__ wght,
                                                     float* __restrict__ out) {
    int k = blockIdx.x * BLOCK + threadIdx.x;
    int n = min(*ofl_cnt, OFL_CAP);
    if (k >= n) return;
    int i = ofl_i[k], t = ofl_t[k];
    int b = i / HW;
    int pix = i - b * HW;
    int h = pix / W, w = pix - h * W;
    int bx = t % TXN, by = t / TXN;
    float2 f = flow[i];
    float x = (float)w + f.x;
    float y = (float)h + f.y;
    float x0f = floorf(x), y0f = floorf(y);
    int x0 = (int)x0f, y0 = (int)y0f;
    float ax = __fsub_rn(x, x0f);
    float ay = __fsub_rn(y, y0f);
    int d = depth_key(f.x, f.y);
    const float* src = im0 + (size_t)b * C * HW + pix;
    float c0 = src[0], c1 = src[HW], c2 = src[2 * HW];
    float wxv[2] = { __fsub_rn(1.0f, ax), ax };
    float wyv[2] = { __fsub_rn(1.0f, ay), ay };
    #pragma unroll
    for (int dy = 0; dy < 2; ++dy) {
        int cy = y0 + dy;
        if ((cy >> 5) != by || cy >= H) continue;
        #pragma unroll
        for (int dx = 0; dx < 2; ++dx) {
            int cx = x0 + dx;
            if ((cx >> 6) != bx) continue;
            int idx = b * HW + cy * W + cx;
            if (dbuf[idx] != d) continue;
            float wg = __fmul_rn(wxv[dx], wyv[dy]);
            atomicAdd(&wght[idx], wg);
            float* o = out + (size_t)b * C * HW + cy * W + cx;
            atomicAdd(&o[0],      __fmul_rn(c0, wg));
            atomicAdd(&o[HW],     __fmul_rn(c1, wg));
            atomicAdd(&o[2 * HW], __fmul_rn(c2, wg));
        }
    }
}

// Norm pass: only active when overflow occurred (k_tile stored raw sums).
__global__ __launch_bounds__(BLOCK) void k_norm(float* __restrict__ out,
                                                const float* __restrict__ wght,
                                                const int* __restrict__ ofl_cnt) {
    if (*ofl_cnt == 0) return;
    int i = blockIdx.x * BLOCK + threadIdx.x;
    if (i >= NPIX) return;
    int b = i / HW;
    int pix = i - b * HW;
    float wv = fmaxf(wght[i], 1e-5f);
    float* o = out + (size_t)b * C * HW + pix;
    o[0]      = __fdiv_rn(o[0], wv);
    o[HW]     = __fdiv_rn(o[HW], wv);
    o[2 * HW] = __fdiv_rn(o[2 * HW], wv);
}

extern "C" void kernel_launch(void* const* d_in, const int* in_sizes, int n_in,
                              void* d_out, int out_size, void* d_ws, size_t ws_size,
                              hipStream_t stream) {
    const float*  im0  = (const float*)d_in[0];   // [B,C,H,W]
    const float2* flow = (const float2*)d_in[1];  // [B,H,W,2] as float2
    float* out = (float*)d_out;                   // [B,C,H,W]

    // Workspace layout (bytes):
    char* ws = (char*)d_ws;
    int*   dbuf    = (int*)ws;                                   // NPIX
    float* wght    = (float*)(ws + (size_t)NPIX * 4);            // NPIX
    int*   cnt     = (int*)(ws + (size_t)NPIX * 8);              // B*NT
    int*   ofl_cnt = cnt + B * NT;                               // 1 (adjacent to cnt)
    int*   ofl_i   = ofl_cnt + 1;                                // OFL_CAP
    int*   ofl_t   = ofl_i + OFL_CAP;                            // OFL_CAP
    int*   bin     = ofl_t + OFL_CAP;                            // B*NT*CAP (~67 MB)

    hipMemsetAsync(dbuf, 0, (size_t)NPIX * 4, stream);
    hipMemsetAsync(cnt, 0, (size_t)(B * NT + 1) * 4, stream);

    int lgrid = NPIX / BLOCK;   // exact: 32400
    dim3 tgrid(TXN, TYN, B);

    k_bin      <<<lgrid, BLOCK, 0, stream>>>(flow, cnt, bin, ofl_cnt, ofl_i, ofl_t, dbuf);
    k_tile     <<<tgrid, BLOCK, 0, stream>>>(im0, flow, cnt, bin, ofl_cnt, dbuf, wght, out);
    k_accum_ofl<<<OFL_CAP / BLOCK, BLOCK, 0, stream>>>(im0, flow, ofl_cnt, ofl_i, ofl_t, dbuf, wght, out);
    k_norm     <<<lgrid, BLOCK, 0, stream>>>(out, wght, ofl_cnt);
}